// Round 7
// baseline (1863.662 us; speedup 1.0000x reference)
//
#include <hip/hip_runtime.h>
#include <math.h>
#include <stdint.h>

#define D 128
#define NG 64
#define NP 625
#define NN 40000
#define NE 400000
#define EH 200000              /* directed edges per direction; rev(e<EH)=e+EH */
#define CCIT 20
#define KPG (NP*NP)            /* 390625 keys per graph */
#define NKEY (NG*KPG)          /* 25,000,000 */
#define NWORD (NKEY/32)        /* 781,250 bitmap words */
#define SCANB ((NWORD+255)/256)/* 3052 scan blocks */
#define NBLKN ((NN+255)/256)   /* 157 scan blocks for node counts */
#define LN_EPSF 1e-5f

/* output layout (floats): x_out | row_out | col_out | edge_attr_out | score */
#define ROW_OFF   ((size_t)NN*D)             /* 5,120,000 */
#define COL_OFF   (ROW_OFF + NE)             /* 5,520,000 */
#define EAOUT_OFF (COL_OFF + NE)             /* 5,920,000 */
#define SCORE_OFF (EAOUT_OFF + (size_t)NE*D) /* 57,120,000 */
#define OUT_TOTAL (SCORE_OFF + NE)           /* 57,520,000 */

__device__ __forceinline__ unsigned fenc(float f) {
  unsigned u = __float_as_uint(f);
  return (u & 0x80000000u) ? ~u : (u | 0x80000000u);
}
__device__ __forceinline__ float fdec(unsigned u) {
  return (u & 0x80000000u) ? __uint_as_float(u & 0x7FFFFFFFu) : __uint_as_float(~u);
}
__device__ __forceinline__ float lanebc(float v, int l) {
  return __int_as_float(__builtin_amdgcn_readlane(__float_as_int(v), l));
}

/* quad-swizzled W^T in global: wq[((d>>2)*128 + j)*4 + (d&3)] = W[j*128+d].
   One dwordx4 per lane fetches w[4dq..4dq+3][j] — 16B/lane coalesced.
   Inner product: 8 rows per wave, lane j owns outputs j and j+64.
   Per-accumulator addition order identical to the original d0-ascending,
   half-paired order (score bits unchanged). */
__device__ __forceinline__ void mm8(const float* __restrict__ wq, int lane,
                                    const float* __restrict__ v0,
                                    const float* __restrict__ v1,
                                    float* __restrict__ a0,
                                    float* __restrict__ a1) {
  const float4* wq4 = (const float4*)wq;
#pragma unroll 2
  for (int dq = 0; dq < 16; dq++) {
    float4 wA = wq4[dq*128 + lane];            /* w[4dq+k][lane]        */
    float4 wB = wq4[dq*128 + lane + 64];       /* w[4dq+k][lane+64]     */
    float4 wC = wq4[(dq+16)*128 + lane];       /* w[64+4dq+k][lane]     */
    float4 wD = wq4[(dq+16)*128 + lane + 64];  /* w[64+4dq+k][lane+64]  */
#pragma unroll
    for (int t = 0; t < 8; t++) {
#pragma unroll
      for (int k = 0; k < 4; k++) {
        float b0 = lanebc(v0[t], dq*4 + k);
        float b1 = lanebc(v1[t], dq*4 + k);
        a0[t] += b0*(&wA.x)[k] + b1*(&wC.x)[k];
        a1[t] += b0*(&wB.x)[k] + b1*(&wD.x)[k];
      }
    }
  }
}

/* ---- transpose+swizzle the 4 weight matrices into workspace ---- */
__global__ void k_transp(const float* __restrict__ kW, const float* __restrict__ vW,
                         const float* __restrict__ g1W, const float* __restrict__ g2W,
                         float* __restrict__ wTk, float* __restrict__ wTv,
                         float* __restrict__ wT1, float* __restrict__ wT2) {
  int i = blockIdx.x*blockDim.x + threadIdx.x;   /* 4*16384 */
  int w = i >> 14, idx = i & 16383;
  int d = idx & 127, j = idx >> 7;               /* read coalesced in d */
  const float* src = (w == 0) ? kW : (w == 1) ? vW : (w == 2) ? g1W : g2W;
  float* dst = (w == 0) ? wTk : (w == 1) ? wTv : (w == 2) ? wT1 : wT2;
  dst[(((d >> 2)*128 + j) << 2) + (d & 3)] = src[j*D + d];
}

/* ---- init: mx = enc(-inf); edge_index_out default = int32-min as float ---- */
__global__ void k_init(unsigned* __restrict__ mx, float* __restrict__ out) {
  int i = blockIdx.x*blockDim.x + threadIdx.x;
  int n = blockDim.x*gridDim.x;
  for (int k = i; k < NN; k += n) mx[k] = 0x007FFFFFu;           /* enc(-inf) */
  for (int k = i; k < 2*NE; k += n) out[ROW_OFF + k] = -2147483648.0f;
}

/* ---- Q = query@qW^T + qb per graph, plus ||Q|| ---- */
__global__ __launch_bounds__(128) void k_qmat(
    const float* __restrict__ query, const float* __restrict__ qW,
    const float* __restrict__ qb, float* __restrict__ Qm, float* __restrict__ qn) {
  int g = blockIdx.x, j = threadIdx.x;
  __shared__ float qs[D];
  __shared__ float red[D];
  qs[j] = query[g*D + j];
  __syncthreads();
  float acc = qb[j];
  for (int d = 0; d < D; d++) acc += qs[d]*qW[j*D + d];
  Qm[g*D + j] = acc;
  red[j] = acc*acc;
  __syncthreads();
  for (int off = 64; off > 0; off >>= 1) {
    if (j < off) red[j] += red[j+off];
    __syncthreads();
  }
  if (j == 0) qn[g] = sqrtf(red[0]);
}

/* ---- counts: in-degree by col ---- */
__global__ void k_count(const int* __restrict__ ei, int* __restrict__ cnt) {
  int stride = blockDim.x*gridDim.x;
  for (int e = blockIdx.x*blockDim.x + threadIdx.x; e < NE; e += stride) {
    atomicAdd(&cnt[ei[NE + e]], 1);
  }
}

/* ---- 3-phase parallel exclusive scan over col counts (40000) ---- */
__global__ __launch_bounds__(256) void k_scanA(
    const int* __restrict__ cnt, int* __restrict__ start, int* __restrict__ bsumN) {
  __shared__ int buf[256];
  int i = blockIdx.x*256 + threadIdx.x;
  int v = (i < NN) ? cnt[i] : 0;
  buf[threadIdx.x] = v;
  __syncthreads();
  for (int o = 1; o < 256; o <<= 1) {
    int x = (threadIdx.x >= o) ? buf[threadIdx.x - o] : 0;
    __syncthreads();
    buf[threadIdx.x] += x;
    __syncthreads();
  }
  if (i < NN) start[i] = buf[threadIdx.x] - v;
  if (threadIdx.x == 255) bsumN[blockIdx.x] = buf[255];
}

__global__ __launch_bounds__(256) void k_scanB(int* __restrict__ bsumN) {
  __shared__ int buf[256];
  int t = threadIdx.x;
  int v = (t < NBLKN) ? bsumN[t] : 0;
  buf[t] = v;
  __syncthreads();
  for (int o = 1; o < 256; o <<= 1) {
    int x = (t >= o) ? buf[t-o] : 0;
    __syncthreads();
    buf[t] += x;
    __syncthreads();
  }
  if (t < NBLKN) bsumN[t] = buf[t] - v;
}

__global__ __launch_bounds__(256) void k_scanC(
    int* __restrict__ start, const int* __restrict__ bsumN) {
  int i = blockIdx.x*256 + threadIdx.x;
  if (i < NN) start[i] += bsumN[blockIdx.x];
  if (i == 0) start[NN] = NE;
}

/* ---- CSR fill (by col). 40k-address atomic: low contention. ---- */
__global__ void k_fillcsr(const int* __restrict__ ei,
                          int* __restrict__ fillc, const int* __restrict__ start,
                          int* __restrict__ csr) {
  int stride = blockDim.x*gridDim.x;
  for (int e = blockIdx.x*blockDim.x + threadIdx.x; e < NE; e += stride) {
    int c = ei[NE + e];
    int s = atomicAdd(&fillc[c], 1);
    csr[start[c] + s] = e;
  }
}

/* ---- sort each node's CSR list (determinism of seg_mean / agg) ---- */
__global__ void k_sortcsr(const int* __restrict__ start, int* __restrict__ csr) {
  int n = blockIdx.x*blockDim.x + threadIdx.x;
  if (n >= NN) return;
  int a = start[n], b = start[n+1];
  for (int i = a+1; i < b; i++) {
    int v = csr[i]; int k = i-1;
    while (k >= a && csr[k] > v) { csr[k+1] = csr[k]; k--; }
    csr[k+1] = v;
  }
}

/* ---- msg = seg_mean(edge_attr, col, N): one wave per node ---- */
__global__ void k_msg(const float* __restrict__ edge_attr, const int* __restrict__ start,
                      const int* __restrict__ csr, float* __restrict__ msg) {
  int wid = (blockIdx.x*blockDim.x + threadIdx.x) >> 6;
  int lane = threadIdx.x & 63;
  if (wid >= NN) return;
  int a = start[wid], b = start[wid+1];
  float s0 = 0.f, s1 = 0.f;
  for (int k = a; k < b; k++) {
    const float* p = edge_attr + (size_t)csr[k]*D;
    s0 += p[lane]; s1 += p[lane+64];
  }
  float c = (float)max(b-a, 1);
  msg[(size_t)wid*D + lane]      = s0/c;
  msg[(size_t)wid*D + lane + 64] = s1/c;
}

/* ---- ea = (edge_attr + msg[row] + x[row]) / 3 ---- */
__global__ void k_ea(const float* __restrict__ edge_attr, const float* __restrict__ msg,
                     const float* __restrict__ x, const int* __restrict__ ei,
                     float* __restrict__ ea) {
  size_t stride = (size_t)blockDim.x*gridDim.x;
  size_t total = (size_t)NE*(D/4);
  for (size_t i = (size_t)blockIdx.x*blockDim.x + threadIdx.x; i < total; i += stride) {
    size_t e = i >> 5;   /* 32 float4 per row */
    int q = (int)(i & 31);
    int r = ei[e];
    float4 A = ((const float4*)(edge_attr + e*D))[q];
    float4 M = ((const float4*)(msg + (size_t)r*D))[q];
    float4 X = ((const float4*)(x + (size_t)r*D))[q];
    float4 o;
    o.x = (A.x + M.x + X.x) / 3.0f;
    o.y = (A.y + M.y + X.y) / 3.0f;
    o.z = (A.z + M.z + X.z) / 3.0f;
    o.w = (A.w + M.w + X.w) / 3.0f;
    ((float4*)(ea + e*D))[q] = o;
  }
}

/* ---- K = unit@kW^T + kb ; score = tanh(K.Q/(|Q||K|))
   score[e] == score[rev[e]] bitwise (unit symmetric, same graph): compute
   e in [0,EH), store both. ---- */
__global__ __launch_bounds__(256, 4) void k_score(
    const float* __restrict__ ea,
    const int* __restrict__ ei, const int* __restrict__ batch,
    const float* __restrict__ wqk, const float* __restrict__ kb,
    const float* __restrict__ Qm, const float* __restrict__ qn,
    float* __restrict__ score_out) {
  const int lane = threadIdx.x & 63;
  const int wid = (blockIdx.x*256 + threadIdx.x) >> 6;
  const int nw = (gridDim.x*256) >> 6;
  const float kb0 = kb[lane], kb1 = kb[lane+64];
  for (int base = wid*8; base < EH; base += nw*8) {
    float v0[8], v1[8], a0[8], a1[8];
#pragma unroll
    for (int t = 0; t < 8; t++) {
      int e = base + t;
      const float* pe = ea + (size_t)e*D;
      const float* pr = ea + (size_t)(e + EH)*D;
      v0[t] = 0.5f*(pe[lane]    + pr[lane]);
      v1[t] = 0.5f*(pe[lane+64] + pr[lane+64]);
      a0[t] = kb0; a1[t] = kb1;
    }
    mm8(wqk, lane, v0, v1, a0, a1);
#pragma unroll
    for (int t = 0; t < 8; t++) {
      int e = base + t;
      int g = batch[ei[e]];
      float q0 = Qm[g*D + lane], q1 = Qm[g*D + lane + 64];
      float p  = a0[t]*q0 + a1[t]*q1;
      float nk = a0[t]*a0[t] + a1[t]*a1[t];
#pragma unroll
      for (int off = 32; off > 0; off >>= 1) {
        p  += __shfl_xor(p,  off, 64);
        nk += __shfl_xor(nk, off, 64);
      }
      if (lane == 0) {
        float s = p / (qn[g] * sqrtf(nk));
        float sv = tanhf(s);
        score_out[e] = sv;
        score_out[e + EH] = sv;
      }
    }
  }
}

/* ---- per-graph score mean: graph g's edges are csr[start[g*NP]..start[(g+1)*NP])
   (each edge once, keyed by col). Deterministic order. Double accumulation. ---- */
__global__ __launch_bounds__(256) void k_mean(
    const float* __restrict__ score, const int* __restrict__ start,
    const int* __restrict__ csr, float* __restrict__ gmean) {
  int g = blockIdx.x;
  int a = start[g*NP], b = start[(g+1)*NP];
  double s = 0.0;
  for (int k = a + threadIdx.x; k < b; k += blockDim.x) s += (double)score[csr[k]];
  __shared__ double red[256];
  red[threadIdx.x] = s;
  __syncthreads();
  for (int off = 128; off > 0; off >>= 1) {
    if (threadIdx.x < off) red[threadIdx.x] += red[threadIdx.x + off];
    __syncthreads();
  }
  if (threadIdx.x == 0) gmean[g] = (float)(red[0] / (double)max(b - a, 1));
}

/* ---- ea2 = LN(prelu(V*score)) in place; perm flags ---- */
__global__ __launch_bounds__(256, 4) void k_vea2(
    float* __restrict__ ea, const float* __restrict__ score,
    const int* __restrict__ ei, const int* __restrict__ batch,
    const float* __restrict__ wqv, const float* __restrict__ vb,
    const float* __restrict__ prelu_a, const float* __restrict__ ln_g,
    const float* __restrict__ ln_b, const float* __restrict__ gmean,
    unsigned char* __restrict__ perm) {
  const int lane = threadIdx.x & 63;
  const int wid = (blockIdx.x*256 + threadIdx.x) >> 6;
  const int nw = (gridDim.x*256) >> 6;
  const float vb0 = vb[lane], vb1 = vb[lane+64];
  const float pa = prelu_a[0];
  const float lg0 = ln_g[lane], lg1 = ln_g[lane+64];
  const float lb0 = ln_b[lane], lb1 = ln_b[lane+64];
  for (int base = wid*8; base < NE; base += nw*8) {
    float v0[8], v1[8], a0[8], a1[8];
#pragma unroll
    for (int t = 0; t < 8; t++) {
      const float* pe = ea + (size_t)(base+t)*D;
      v0[t] = pe[lane]; v1[t] = pe[lane+64];
      a0[t] = vb0; a1[t] = vb1;
    }
    mm8(wqv, lane, v0, v1, a0, a1);
#pragma unroll
    for (int t = 0; t < 8; t++) {
      int e = base + t;
      float s = score[e];
      float y0 = a0[t]*s, y1 = a1[t]*s;
      y0 = (y0 >= 0.f) ? y0 : pa*y0;
      y1 = (y1 >= 0.f) ? y1 : pa*y1;
      float tot = y0 + y1;
#pragma unroll
      for (int off = 32; off > 0; off >>= 1) tot += __shfl_xor(tot, off, 64);
      float mu = tot * (1.0f/128.0f);
      float d0v = y0 - mu, d1v = y1 - mu;
      float sq = d0v*d0v + d1v*d1v;
#pragma unroll
      for (int off = 32; off > 0; off >>= 1) sq += __shfl_xor(sq, off, 64);
      float inv = rsqrtf(sq*(1.0f/128.0f) + LN_EPSF);
      float* po = ea + (size_t)e*D;
      po[lane]      = d0v*inv*lg0 + lb0;
      po[lane + 64] = d1v*inv*lg1 + lb1;
      if (lane == 0) {
        int g = batch[ei[e]];
        perm[e] = (unsigned char)((s < gmean[g]) && (s <= 0.0f));
      }
    }
  }
}

/* ---- connected components: one block per graph, all 20 iters in LDS. ---- */
__global__ __launch_bounds__(256) void k_cc(
    const int* __restrict__ ei, const unsigned char* __restrict__ perm,
    const int* __restrict__ start, const int* __restrict__ csr,
    int* __restrict__ comp) {
  __shared__ unsigned short er[8192], ec[8192];
  __shared__ int lab[NP], tmp[NP];
  __shared__ int cnt;
  int g = blockIdx.x;
  int base = g*NP;
  if (threadIdx.x == 0) cnt = 0;
  for (int i = threadIdx.x; i < NP; i += blockDim.x) lab[i] = i;
  __syncthreads();
  int a = start[base], b = start[base + NP];
  for (int k = a + threadIdx.x; k < b; k += blockDim.x) {
    int e = csr[k];
    if (perm[e]) {
      int idx = atomicAdd(&cnt, 1);
      if (idx < 8192) {
        er[idx] = (unsigned short)(ei[e] - base);
        ec[idx] = (unsigned short)(ei[NE + e] - base);
      }
    }
  }
  __syncthreads();
  int m = min(cnt, 8192);
  for (int it = 0; it < CCIT; it++) {
    for (int k = threadIdx.x; k < m; k += blockDim.x) {
      int r = er[k], c = ec[k];
      atomicMin(&lab[r], lab[c]);
      atomicMin(&lab[c], lab[r]);
    }
    __syncthreads();
    for (int i = threadIdx.x; i < NP; i += blockDim.x) tmp[i] = lab[lab[i]];
    __syncthreads();
    for (int i = threadIdx.x; i < NP; i += blockDim.x) lab[i] = tmp[tmp[i]];
    __syncthreads();
  }
  for (int i = threadIdx.x; i < NP; i += blockDim.x) comp[base + i] = base + lab[i];
}

/* ---- GINE aggregate: h = x + segsum(perm ? relu(x[row]+ea2) : 0, col) ---- */
__global__ void k_gine(const float* __restrict__ x, const float* __restrict__ ea2,
                       const int* __restrict__ ei, const unsigned char* __restrict__ perm,
                       const int* __restrict__ start, const int* __restrict__ csr,
                       float* __restrict__ h) {
  int wid = (blockIdx.x*blockDim.x + threadIdx.x) >> 6;
  int lane = threadIdx.x & 63;
  if (wid >= NN) return;
  int a = start[wid], b = start[wid+1];
  float s0 = 0.f, s1 = 0.f;
  for (int k = a; k < b; k++) {
    int e = csr[k];
    if (!perm[e]) continue;
    int r = ei[e];
    const float* pe = ea2 + (size_t)e*D;
    const float* px = x + (size_t)r*D;
    s0 += fmaxf(px[lane]      + pe[lane],      0.f);
    s1 += fmaxf(px[lane + 64] + pe[lane + 64], 0.f);
  }
  h[(size_t)wid*D + lane]      = x[(size_t)wid*D + lane]      + s0;
  h[(size_t)wid*D + lane + 64] = x[(size_t)wid*D + lane + 64] + s1;
}

/* ---- generic row matmul out = act(in@W^T + b) ---- */
__global__ __launch_bounds__(256, 4) void k_rowmm(
    const float* __restrict__ in, const float* __restrict__ wq,
    const float* __restrict__ bias, float* __restrict__ out,
    int nrows, int do_relu) {
  const int lane = threadIdx.x & 63;
  const int wid = (blockIdx.x*256 + threadIdx.x) >> 6;
  const int nw = (gridDim.x*256) >> 6;
  const float b0r = bias[lane], b1r = bias[lane+64];
  for (int base = wid*8; base < nrows; base += nw*8) {
    float v0[8], v1[8], a0[8], a1[8];
#pragma unroll
    for (int t = 0; t < 8; t++) {
      const float* pe = in + (size_t)(base+t)*D;
      v0[t] = pe[lane]; v1[t] = pe[lane+64];
      a0[t] = b0r; a1[t] = b1r;
    }
    mm8(wq, lane, v0, v1, a0, a1);
#pragma unroll
    for (int t = 0; t < 8; t++) {
      float o0 = a0[t], o1 = a1[t];
      if (do_relu) { o0 = fmaxf(o0, 0.f); o1 = fmaxf(o1, 0.f); }
      float* po = out + (size_t)(base+t)*D;
      po[lane] = o0; po[lane+64] = o1;
    }
  }
}

/* ---- logit + per-component max ---- */
__global__ void k_logit(const float* __restrict__ xs, const float* __restrict__ attnW,
                        const int* __restrict__ comp, float* __restrict__ logit,
                        unsigned* __restrict__ mx) {
  int wid = (blockIdx.x*blockDim.x + threadIdx.x) >> 6;
  int lane = threadIdx.x & 63;
  if (wid >= NN) return;
  float p = xs[(size_t)wid*D + lane]*attnW[lane] + xs[(size_t)wid*D + lane + 64]*attnW[lane + 64];
#pragma unroll
  for (int off = 32; off > 0; off >>= 1) p += __shfl_xor(p, off, 64);
  if (lane == 0) {
    float l = (p >= 0.f) ? p : 0.01f*p;   /* leaky_relu */
    logit[wid] = l;
    atomicMax(&mx[comp[wid]], fenc(l));
  }
}

__global__ void k_expden(const float* __restrict__ logit, const int* __restrict__ comp,
                         const unsigned* __restrict__ mx, float* __restrict__ exv,
                         float* __restrict__ den) {
  int n = blockIdx.x*blockDim.x + threadIdx.x;
  if (n >= NN) return;
  float m = fdec(mx[comp[n]]);
  float e = expf(logit[n] - m);
  exv[n] = e;
  atomicAdd(&den[comp[n]], e);
}

__global__ void k_pool(const float* __restrict__ xs, const float* __restrict__ exv,
                       const float* __restrict__ den, const int* __restrict__ comp,
                       float* __restrict__ xout) {
  int wid = (blockIdx.x*blockDim.x + threadIdx.x) >> 6;
  int lane = threadIdx.x & 63;
  if (wid >= NN) return;
  float w = exv[wid] / den[comp[wid]];
  size_t dst = (size_t)comp[wid]*D;
  atomicAdd(&xout[dst + lane],      w*xs[(size_t)wid*D + lane]);
  atomicAdd(&xout[dst + lane + 64], w*xs[(size_t)wid*D + lane + 64]);
}

/* ---- coalesce: key presence bitmap ---- */
__global__ void k_bitmap(const int* __restrict__ ei, const int* __restrict__ comp,
                         const int* __restrict__ batch, unsigned* __restrict__ bitmap,
                         int* __restrict__ validcnt) {
  __shared__ int lv;
  if (threadIdx.x == 0) lv = 0;
  __syncthreads();
  int stride = blockDim.x*gridDim.x;
  for (int e = blockIdx.x*blockDim.x + threadIdx.x; e < NE; e += stride) {
    int r = ei[e], c = ei[NE + e];
    int rc = comp[r], cc = comp[c];
    if (rc != cc) {
      int g = batch[r];
      int lr = rc - g*NP, lc = cc - g*NP;
      if ((unsigned)lr < NP && (unsigned)lc < NP) {
        int ck = g*KPG + lr*NP + lc;
        atomicOr(&bitmap[ck >> 5], 1u << (ck & 31));
        atomicAdd(&lv, 1);
      }
    }
  }
  __syncthreads();
  if (threadIdx.x == 0) atomicAdd(validcnt, lv);
}

/* ---- popcount prefix scan: per-block ---- */
__global__ __launch_bounds__(256) void k_scan1(const unsigned* __restrict__ bitmap,
                                               unsigned* __restrict__ wpref,
                                               unsigned* __restrict__ bsum) {
  __shared__ unsigned buf[256];
  int i = blockIdx.x*256 + threadIdx.x;
  unsigned v = (i < NWORD) ? (unsigned)__popc(bitmap[i]) : 0u;
  buf[threadIdx.x] = v;
  __syncthreads();
  for (int o = 1; o < 256; o <<= 1) {
    unsigned x = (threadIdx.x >= o) ? buf[threadIdx.x - o] : 0u;
    __syncthreads();
    buf[threadIdx.x] += x;
    __syncthreads();
  }
  if (i < NWORD) wpref[i] = buf[threadIdx.x] - v;
  if (threadIdx.x == 255) bsum[blockIdx.x] = buf[255];
}

__global__ __launch_bounds__(256) void k_scan2(unsigned* __restrict__ bsum,
                                               int* __restrict__ U) {
  __shared__ unsigned buf[256];
  __shared__ unsigned carry;
  int t = threadIdx.x;
  if (t == 0) carry = 0;
  __syncthreads();
  for (int base = 0; base < SCANB; base += 256) {
    int i = base + t;
    unsigned v = (i < SCANB) ? bsum[i] : 0u;
    buf[t] = v; __syncthreads();
    for (int o = 1; o < 256; o <<= 1) {
      unsigned x = (t >= o) ? buf[t-o] : 0u;
      __syncthreads();
      buf[t] += x;
      __syncthreads();
    }
    if (i < SCANB) bsum[i] = carry + buf[t] - v;
    unsigned tot = buf[255];
    __syncthreads();
    if (t == 0) carry += tot;
    __syncthreads();
  }
  if (t == 0) *U = (int)carry;
}

__global__ void k_scan3(unsigned* __restrict__ wpref, const unsigned* __restrict__ bsum) {
  int i = blockIdx.x*256 + threadIdx.x;
  if (i < NWORD) wpref[i] += bsum[blockIdx.x];
}

/* ---- scatter coalesced edge_attr + edge_index ---- */
__global__ void k_coalesce(const int* __restrict__ ei, const int* __restrict__ comp,
                           const int* __restrict__ batch, const float* __restrict__ ea2,
                           const unsigned* __restrict__ bitmap, const unsigned* __restrict__ wpref,
                           float* __restrict__ out) {
  const int lane = threadIdx.x & 63;
  int wid = (blockIdx.x*blockDim.x + threadIdx.x) >> 6;
  int nw = (gridDim.x*blockDim.x) >> 6;
  for (int e = wid; e < NE; e += nw) {
    int r = ei[e], c = ei[NE + e];
    int rc = comp[r], cc = comp[c];
    if (rc == cc) continue;
    int g = batch[r];
    int lr = rc - g*NP, lc = cc - g*NP;
    if ((unsigned)lr >= NP || (unsigned)lc >= NP) continue;
    int ck = g*KPG + lr*NP + lc;
    int wd = ck >> 5, bit = ck & 31;
    unsigned rank = wpref[wd] + (unsigned)__popc(bitmap[wd] & ((1u << bit) - 1u));
    const float* pe = ea2 + (size_t)e*D;
    float* po = out + EAOUT_OFF + (size_t)rank*D;
    atomicAdd(&po[lane],      pe[lane]);
    atomicAdd(&po[lane + 64], pe[lane + 64]);
    if (lane == 0) {
      out[ROW_OFF + rank] = (float)rc;
      out[COL_OFF + rank] = (float)cc;
    }
  }
}

__global__ void k_tail(const int* __restrict__ U, const int* __restrict__ validcnt,
                       float* __restrict__ out) {
  if (blockIdx.x == 0 && threadIdx.x == 0) {
    int u = *U;
    if (*validcnt < NE && u < NE) {
      out[ROW_OFF + u] = -1.0f;
      out[COL_OFF + u] = -1.0f;
    }
  }
}

extern "C" void kernel_launch(void* const* d_in, const int* in_sizes, int n_in,
                              void* d_out, int out_size, void* d_ws, size_t ws_size,
                              hipStream_t stream) {
  const float* x         = (const float*)d_in[0];
  const float* edge_attr = (const float*)d_in[1];
  const float* query     = (const float*)d_in[2];
  const float* qW = (const float*)d_in[3];
  const float* qb = (const float*)d_in[4];
  const float* kW = (const float*)d_in[5];
  const float* kb = (const float*)d_in[6];
  const float* vW = (const float*)d_in[7];
  const float* vb = (const float*)d_in[8];
  const float* prelu_a = (const float*)d_in[9];
  const float* ln_g = (const float*)d_in[10];
  const float* ln_b = (const float*)d_in[11];
  const float* attnW = (const float*)d_in[12];
  const float* g1W = (const float*)d_in[13];
  const float* g1b = (const float*)d_in[14];
  const float* g2W = (const float*)d_in[15];
  const float* g2b = (const float*)d_in[16];
  const int* ei    = (const int*)d_in[17];
  const int* batch = (const int*)d_in[18];
  const int* rev   = (const int*)d_in[19];
  float* out = (float*)d_out;
  (void)in_sizes; (void)n_in; (void)out_size; (void)rev;

  char* w = (char*)d_ws;
  size_t off = 0;
  auto alloc = [&](size_t bytes) -> void* {
    void* p = w + off;
    off = (off + bytes + 255) & ~(size_t)255;
    return p;
  };
  float* ea = (float*)alloc((size_t)NE*D*4);
  float* h  = (float*)alloc((size_t)NN*D*4);   /* msg, then h */
  float* t1 = (float*)alloc((size_t)NN*D*4);
  float* xs = (float*)alloc((size_t)NN*D*4);
  float* Qm = (float*)alloc((size_t)NG*D*4);
  float* qn = (float*)alloc(NG*4);
  float* gmean = (float*)alloc(NG*4);
  float* wTk = (float*)alloc((size_t)D*D*4);
  float* wTv = (float*)alloc((size_t)D*D*4);
  float* wT1 = (float*)alloc((size_t)D*D*4);
  float* wT2 = (float*)alloc((size_t)D*D*4);
  int* comp   = (int*)alloc((size_t)NN*4);
  float* logit = (float*)alloc((size_t)NN*4);
  float* exv   = (float*)alloc((size_t)NN*4);
  int* startc = (int*)alloc((size_t)(NN+1)*4);
  int* csr    = (int*)alloc((size_t)NE*4);
  unsigned char* perm = (unsigned char*)alloc(NE);
  unsigned* wpref = (unsigned*)alloc((size_t)NWORD*4);
  unsigned* bsum  = (unsigned*)alloc((size_t)(SCANB+32)*4);
  int* bsumN = (int*)alloc((size_t)(NBLKN+32)*4);
  int* Uv = (int*)alloc(256);
  unsigned* mx = (unsigned*)alloc((size_t)NN*4);
  /* zero region (single memset) */
  size_t z0 = off;
  int* cnt   = (int*)alloc((size_t)NN*4);
  int* fillc = (int*)alloc((size_t)NN*4);
  float* den = (float*)alloc((size_t)NN*4);
  int* validcnt = (int*)alloc(256);
  unsigned* bitmap = (unsigned*)alloc((size_t)NWORD*4);
  size_t z1 = off;
  if (off > ws_size) return;  /* workspace too small: fail visibly */

  hipMemsetAsync(d_out, 0, OUT_TOTAL*4, stream);
  hipMemsetAsync(w + z0, 0, z1 - z0, stream);

  k_transp<<<256, 256, 0, stream>>>(kW, vW, g1W, g2W, wTk, wTv, wT1, wT2);
  k_init<<<1024, 256, 0, stream>>>(mx, out);
  k_qmat<<<NG, 128, 0, stream>>>(query, qW, qb, Qm, qn);
  k_count<<<512, 256, 0, stream>>>(ei, cnt);
  k_scanA<<<NBLKN, 256, 0, stream>>>(cnt, startc, bsumN);
  k_scanB<<<1, 256, 0, stream>>>(bsumN);
  k_scanC<<<NBLKN, 256, 0, stream>>>(startc, bsumN);
  k_fillcsr<<<512, 256, 0, stream>>>(ei, fillc, startc, csr);
  k_sortcsr<<<(NN+255)/256, 256, 0, stream>>>(startc, csr);
  k_msg<<<NN/4, 256, 0, stream>>>(edge_attr, startc, csr, h);
  k_ea<<<8192, 256, 0, stream>>>(edge_attr, h, x, ei, ea);
  k_score<<<2048, 256, 0, stream>>>(ea, ei, batch, wTk, kb, Qm, qn, out + SCORE_OFF);
  k_mean<<<NG, 256, 0, stream>>>(out + SCORE_OFF, startc, csr, gmean);
  k_vea2<<<2048, 256, 0, stream>>>(ea, out + SCORE_OFF, ei, batch, wTv, vb,
                                   prelu_a, ln_g, ln_b, gmean, perm);
  k_cc<<<NG, 256, 0, stream>>>(ei, perm, startc, csr, comp);
  k_gine<<<NN/4, 256, 0, stream>>>(x, ea, ei, perm, startc, csr, h);
  k_rowmm<<<1024, 256, 0, stream>>>(h, wT1, g1b, t1, NN, 1);
  k_rowmm<<<1024, 256, 0, stream>>>(t1, wT2, g2b, xs, NN, 0);
  k_logit<<<NN/4, 256, 0, stream>>>(xs, attnW, comp, logit, mx);
  k_expden<<<(NN+255)/256, 256, 0, stream>>>(logit, comp, mx, exv, den);
  k_pool<<<NN/4, 256, 0, stream>>>(xs, exv, den, comp, out);
  k_bitmap<<<512, 256, 0, stream>>>(ei, comp, batch, bitmap, validcnt);
  k_scan1<<<SCANB, 256, 0, stream>>>(bitmap, wpref, bsum);
  k_scan2<<<1, 256, 0, stream>>>(bsum, Uv);
  k_scan3<<<SCANB, 256, 0, stream>>>(wpref, bsum);
  k_coalesce<<<2048, 256, 0, stream>>>(ei, comp, batch, ea, bitmap, wpref, out);
  k_tail<<<1, 64, 0, stream>>>(Uv, validcnt, out);
}

// Round 8
// 1619.143 us; speedup vs baseline: 1.1510x; 1.1510x over previous
//
#include <hip/hip_runtime.h>
#include <math.h>
#include <stdint.h>

#define D 128
#define NG 64
#define NP 625
#define NN 40000
#define NE 400000
#define EH 200000              /* directed edges per direction; rev(e<EH)=e+EH */
#define CCIT 20
#define KPG (NP*NP)            /* 390625 keys per graph */
#define NKEY (NG*KPG)          /* 25,000,000 */
#define NWORD (NKEY/32)        /* 781,250 bitmap words */
#define SCANB ((NWORD+255)/256)/* 3052 scan blocks */
#define NBLKN ((NN+255)/256)   /* 157 scan blocks for node counts */
#define LN_EPSF 1e-5f

/* output layout (floats): x_out | row_out | col_out | edge_attr_out | score */
#define ROW_OFF   ((size_t)NN*D)             /* 5,120,000 */
#define COL_OFF   (ROW_OFF + NE)             /* 5,520,000 */
#define EAOUT_OFF (COL_OFF + NE)             /* 5,920,000 */
#define SCORE_OFF (EAOUT_OFF + (size_t)NE*D) /* 57,120,000 */
#define OUT_TOTAL (SCORE_OFF + NE)           /* 57,520,000 */

__device__ __forceinline__ unsigned fenc(float f) {
  unsigned u = __float_as_uint(f);
  return (u & 0x80000000u) ? ~u : (u | 0x80000000u);
}
__device__ __forceinline__ float fdec(unsigned u) {
  return (u & 0x80000000u) ? __uint_as_float(u & 0x7FFFFFFFu) : __uint_as_float(~u);
}

/* LDS-broadcast inner product. 8 rows per wave, lane j owns outputs j, j+64.
   b-values come from a WAVE-PRIVATE LDS buffer (staged by the same wave, no
   barrier needed) read at a wave-uniform address -> HW broadcast on the LDS
   pipe, no conflicts, zero VALU broadcast cost. Weights are quad-swizzled in
   global (wq[((d>>2)*128+j)*4+(d&3)] = W[j*128+d]): one dwordx4 per lane =
   16B/lane coalesced; the 64KB matrix streams from L2.
   Accumulation order per output: dq 0..15, k 0..3, halves paired — bitwise
   identical to the previous rounds' order (scores unchanged). */
__device__ __forceinline__ void mm8l(const float* __restrict__ wq,
                                     const float* __restrict__ wb, /* LDS, 8*128 */
                                     int lane,
                                     float* __restrict__ a0,
                                     float* __restrict__ a1) {
  const float4* wq4 = (const float4*)wq;
  const float4* b4  = (const float4*)wb;
#pragma unroll 2
  for (int dq = 0; dq < 16; dq++) {
    float4 wA = wq4[dq*128 + lane];            /* w[4dq+k][lane]        */
    float4 wB = wq4[dq*128 + lane + 64];       /* w[4dq+k][lane+64]     */
    float4 wC = wq4[(dq+16)*128 + lane];       /* w[64+4dq+k][lane]     */
    float4 wD = wq4[(dq+16)*128 + lane + 64];  /* w[64+4dq+k][lane+64]  */
#pragma unroll
    for (int t = 0; t < 8; t++) {
      float4 bL = b4[t*32 + dq];               /* v[4dq..4dq+3]    */
      float4 bH = b4[t*32 + 16 + dq];          /* v[64+4dq..]      */
#pragma unroll
      for (int k = 0; k < 4; k++) {
        a0[t] += (&bL.x)[k]*(&wA.x)[k] + (&bH.x)[k]*(&wC.x)[k];
        a1[t] += (&bL.x)[k]*(&wB.x)[k] + (&bH.x)[k]*(&wD.x)[k];
      }
    }
  }
}

/* ---- transpose+swizzle the 4 weight matrices into workspace ---- */
__global__ void k_transp(const float* __restrict__ kW, const float* __restrict__ vW,
                         const float* __restrict__ g1W, const float* __restrict__ g2W,
                         float* __restrict__ wTk, float* __restrict__ wTv,
                         float* __restrict__ wT1, float* __restrict__ wT2) {
  int i = blockIdx.x*blockDim.x + threadIdx.x;   /* 4*16384 */
  int w = i >> 14, idx = i & 16383;
  int d = idx & 127, j = idx >> 7;               /* read coalesced in d */
  const float* src = (w == 0) ? kW : (w == 1) ? vW : (w == 2) ? g1W : g2W;
  float* dst = (w == 0) ? wTk : (w == 1) ? wTv : (w == 2) ? wT1 : wT2;
  dst[(((d >> 2)*128 + j) << 2) + (d & 3)] = src[j*D + d];
}

/* ---- init: mx = enc(-inf); edge_index_out default = int32-min as float ---- */
__global__ void k_init(unsigned* __restrict__ mx, float* __restrict__ out) {
  int i = blockIdx.x*blockDim.x + threadIdx.x;
  int n = blockDim.x*gridDim.x;
  for (int k = i; k < NN; k += n) mx[k] = 0x007FFFFFu;           /* enc(-inf) */
  for (int k = i; k < 2*NE; k += n) out[ROW_OFF + k] = -2147483648.0f;
}

/* ---- Q = query@qW^T + qb per graph, plus ||Q|| ---- */
__global__ __launch_bounds__(128) void k_qmat(
    const float* __restrict__ query, const float* __restrict__ qW,
    const float* __restrict__ qb, float* __restrict__ Qm, float* __restrict__ qn) {
  int g = blockIdx.x, j = threadIdx.x;
  __shared__ float qs[D];
  __shared__ float red[D];
  qs[j] = query[g*D + j];
  __syncthreads();
  float acc = qb[j];
  for (int d = 0; d < D; d++) acc += qs[d]*qW[j*D + d];
  Qm[g*D + j] = acc;
  red[j] = acc*acc;
  __syncthreads();
  for (int off = 64; off > 0; off >>= 1) {
    if (j < off) red[j] += red[j+off];
    __syncthreads();
  }
  if (j == 0) qn[g] = sqrtf(red[0]);
}

/* ---- counts: in-degree by col ---- */
__global__ void k_count(const int* __restrict__ ei, int* __restrict__ cnt) {
  int stride = blockDim.x*gridDim.x;
  for (int e = blockIdx.x*blockDim.x + threadIdx.x; e < NE; e += stride) {
    atomicAdd(&cnt[ei[NE + e]], 1);
  }
}

/* ---- 3-phase parallel exclusive scan over col counts (40000) ---- */
__global__ __launch_bounds__(256) void k_scanA(
    const int* __restrict__ cnt, int* __restrict__ start, int* __restrict__ bsumN) {
  __shared__ int buf[256];
  int i = blockIdx.x*256 + threadIdx.x;
  int v = (i < NN) ? cnt[i] : 0;
  buf[threadIdx.x] = v;
  __syncthreads();
  for (int o = 1; o < 256; o <<= 1) {
    int x = (threadIdx.x >= o) ? buf[threadIdx.x - o] : 0;
    __syncthreads();
    buf[threadIdx.x] += x;
    __syncthreads();
  }
  if (i < NN) start[i] = buf[threadIdx.x] - v;
  if (threadIdx.x == 255) bsumN[blockIdx.x] = buf[255];
}

__global__ __launch_bounds__(256) void k_scanB(int* __restrict__ bsumN) {
  __shared__ int buf[256];
  int t = threadIdx.x;
  int v = (t < NBLKN) ? bsumN[t] : 0;
  buf[t] = v;
  __syncthreads();
  for (int o = 1; o < 256; o <<= 1) {
    int x = (t >= o) ? buf[t-o] : 0;
    __syncthreads();
    buf[t] += x;
    __syncthreads();
  }
  if (t < NBLKN) bsumN[t] = buf[t] - v;
}

__global__ __launch_bounds__(256) void k_scanC(
    int* __restrict__ start, const int* __restrict__ bsumN) {
  int i = blockIdx.x*256 + threadIdx.x;
  if (i < NN) start[i] += bsumN[blockIdx.x];
  if (i == 0) start[NN] = NE;
}

/* ---- CSR fill (by col). 40k-address atomic: low contention. ---- */
__global__ void k_fillcsr(const int* __restrict__ ei,
                          int* __restrict__ fillc, const int* __restrict__ start,
                          int* __restrict__ csr) {
  int stride = blockDim.x*gridDim.x;
  for (int e = blockIdx.x*blockDim.x + threadIdx.x; e < NE; e += stride) {
    int c = ei[NE + e];
    int s = atomicAdd(&fillc[c], 1);
    csr[start[c] + s] = e;
  }
}

/* ---- sort each node's CSR list (determinism of seg_mean / agg) ---- */
__global__ void k_sortcsr(const int* __restrict__ start, int* __restrict__ csr) {
  int n = blockIdx.x*blockDim.x + threadIdx.x;
  if (n >= NN) return;
  int a = start[n], b = start[n+1];
  for (int i = a+1; i < b; i++) {
    int v = csr[i]; int k = i-1;
    while (k >= a && csr[k] > v) { csr[k+1] = csr[k]; k--; }
    csr[k+1] = v;
  }
}

/* ---- msg = seg_mean(edge_attr, col, N): one wave per node ---- */
__global__ void k_msg(const float* __restrict__ edge_attr, const int* __restrict__ start,
                      const int* __restrict__ csr, float* __restrict__ msg) {
  int wid = (blockIdx.x*blockDim.x + threadIdx.x) >> 6;
  int lane = threadIdx.x & 63;
  if (wid >= NN) return;
  int a = start[wid], b = start[wid+1];
  float s0 = 0.f, s1 = 0.f;
  for (int k = a; k < b; k++) {
    const float* p = edge_attr + (size_t)csr[k]*D;
    s0 += p[lane]; s1 += p[lane+64];
  }
  float c = (float)max(b-a, 1);
  msg[(size_t)wid*D + lane]      = s0/c;
  msg[(size_t)wid*D + lane + 64] = s1/c;
}

/* ---- ea = (edge_attr + msg[row] + x[row]) / 3 ---- */
__global__ void k_ea(const float* __restrict__ edge_attr, const float* __restrict__ msg,
                     const float* __restrict__ x, const int* __restrict__ ei,
                     float* __restrict__ ea) {
  size_t stride = (size_t)blockDim.x*gridDim.x;
  size_t total = (size_t)NE*(D/4);
  for (size_t i = (size_t)blockIdx.x*blockDim.x + threadIdx.x; i < total; i += stride) {
    size_t e = i >> 5;   /* 32 float4 per row */
    int q = (int)(i & 31);
    int r = ei[e];
    float4 A = ((const float4*)(edge_attr + e*D))[q];
    float4 M = ((const float4*)(msg + (size_t)r*D))[q];
    float4 X = ((const float4*)(x + (size_t)r*D))[q];
    float4 o;
    o.x = (A.x + M.x + X.x) / 3.0f;
    o.y = (A.y + M.y + X.y) / 3.0f;
    o.z = (A.z + M.z + X.z) / 3.0f;
    o.w = (A.w + M.w + X.w) / 3.0f;
    ((float4*)(ea + e*D))[q] = o;
  }
}

/* ---- K = unit@kW^T + kb ; score = tanh(K.Q/(|Q||K|))
   score[e] == score[rev[e]] bitwise (unit symmetric, same graph): compute
   e in [0,EH), store both. Wave-private LDS staging (16KB/block). ---- */
__global__ __launch_bounds__(256) void k_score(
    const float* __restrict__ ea,
    const int* __restrict__ ei, const int* __restrict__ batch,
    const float* __restrict__ wqk, const float* __restrict__ kb,
    const float* __restrict__ Qm, const float* __restrict__ qn,
    float* __restrict__ score_out) {
  __shared__ float sbuf[4][8*D];
  float* wb = sbuf[threadIdx.x >> 6];
  const int lane = threadIdx.x & 63;
  const int wid = (blockIdx.x*256 + threadIdx.x) >> 6;
  const int nw = (gridDim.x*256) >> 6;
  const float kb0 = kb[lane], kb1 = kb[lane+64];
  for (int base = wid*8; base < EH; base += nw*8) {
    float a0[8], a1[8];
#pragma unroll
    for (int t = 0; t < 8; t++) {
      int e = base + t;
      const float* pe = ea + (size_t)e*D;
      const float* pr = ea + (size_t)(e + EH)*D;
      wb[t*D + lane]      = 0.5f*(pe[lane]    + pr[lane]);
      wb[t*D + lane + 64] = 0.5f*(pe[lane+64] + pr[lane+64]);
      a0[t] = kb0; a1[t] = kb1;
    }
    mm8l(wqk, wb, lane, a0, a1);
#pragma unroll
    for (int t = 0; t < 8; t++) {
      int e = base + t;
      int g = batch[ei[e]];
      float q0 = Qm[g*D + lane], q1 = Qm[g*D + lane + 64];
      float p  = a0[t]*q0 + a1[t]*q1;
      float nk = a0[t]*a0[t] + a1[t]*a1[t];
#pragma unroll
      for (int off = 32; off > 0; off >>= 1) {
        p  += __shfl_xor(p,  off, 64);
        nk += __shfl_xor(nk, off, 64);
      }
      if (lane == 0) {
        float s = p / (qn[g] * sqrtf(nk));
        float sv = tanhf(s);
        score_out[e] = sv;
        score_out[e + EH] = sv;
      }
    }
  }
}

/* ---- per-graph score mean: graph g's edges are csr[start[g*NP]..start[(g+1)*NP])
   (each edge once, keyed by col). Deterministic order. Double accumulation. ---- */
__global__ __launch_bounds__(256) void k_mean(
    const float* __restrict__ score, const int* __restrict__ start,
    const int* __restrict__ csr, float* __restrict__ gmean) {
  int g = blockIdx.x;
  int a = start[g*NP], b = start[(g+1)*NP];
  double s = 0.0;
  for (int k = a + threadIdx.x; k < b; k += blockDim.x) s += (double)score[csr[k]];
  __shared__ double red[256];
  red[threadIdx.x] = s;
  __syncthreads();
  for (int off = 128; off > 0; off >>= 1) {
    if (threadIdx.x < off) red[threadIdx.x] += red[threadIdx.x + off];
    __syncthreads();
  }
  if (threadIdx.x == 0) gmean[g] = (float)(red[0] / (double)max(b - a, 1));
}

/* ---- ea2 = LN(prelu(V*score)) in place; perm flags ---- */
__global__ __launch_bounds__(256) void k_vea2(
    float* __restrict__ ea, const float* __restrict__ score,
    const int* __restrict__ ei, const int* __restrict__ batch,
    const float* __restrict__ wqv, const float* __restrict__ vb,
    const float* __restrict__ prelu_a, const float* __restrict__ ln_g,
    const float* __restrict__ ln_b, const float* __restrict__ gmean,
    unsigned char* __restrict__ perm) {
  __shared__ float sbuf[4][8*D];
  float* wb = sbuf[threadIdx.x >> 6];
  const int lane = threadIdx.x & 63;
  const int wid = (blockIdx.x*256 + threadIdx.x) >> 6;
  const int nw = (gridDim.x*256) >> 6;
  const float vb0 = vb[lane], vb1 = vb[lane+64];
  const float pa = prelu_a[0];
  const float lg0 = ln_g[lane], lg1 = ln_g[lane+64];
  const float lb0 = ln_b[lane], lb1 = ln_b[lane+64];
  for (int base = wid*8; base < NE; base += nw*8) {
    float a0[8], a1[8];
#pragma unroll
    for (int t = 0; t < 8; t++) {
      const float* pe = ea + (size_t)(base+t)*D;
      wb[t*D + lane]      = pe[lane];
      wb[t*D + lane + 64] = pe[lane+64];
      a0[t] = vb0; a1[t] = vb1;
    }
    mm8l(wqv, wb, lane, a0, a1);
#pragma unroll
    for (int t = 0; t < 8; t++) {
      int e = base + t;
      float s = score[e];
      float y0 = a0[t]*s, y1 = a1[t]*s;
      y0 = (y0 >= 0.f) ? y0 : pa*y0;
      y1 = (y1 >= 0.f) ? y1 : pa*y1;
      float tot = y0 + y1;
#pragma unroll
      for (int off = 32; off > 0; off >>= 1) tot += __shfl_xor(tot, off, 64);
      float mu = tot * (1.0f/128.0f);
      float d0v = y0 - mu, d1v = y1 - mu;
      float sq = d0v*d0v + d1v*d1v;
#pragma unroll
      for (int off = 32; off > 0; off >>= 1) sq += __shfl_xor(sq, off, 64);
      float inv = rsqrtf(sq*(1.0f/128.0f) + LN_EPSF);
      float* po = ea + (size_t)e*D;
      po[lane]      = d0v*inv*lg0 + lb0;
      po[lane + 64] = d1v*inv*lg1 + lb1;
      if (lane == 0) {
        int g = batch[ei[e]];
        perm[e] = (unsigned char)((s < gmean[g]) && (s <= 0.0f));
      }
    }
  }
}

/* ---- connected components: one block per graph, all 20 iters in LDS. ---- */
__global__ __launch_bounds__(256) void k_cc(
    const int* __restrict__ ei, const unsigned char* __restrict__ perm,
    const int* __restrict__ start, const int* __restrict__ csr,
    int* __restrict__ comp) {
  __shared__ unsigned short er[8192], ec[8192];
  __shared__ int lab[NP], tmp[NP];
  __shared__ int cnt;
  int g = blockIdx.x;
  int base = g*NP;
  if (threadIdx.x == 0) cnt = 0;
  for (int i = threadIdx.x; i < NP; i += blockDim.x) lab[i] = i;
  __syncthreads();
  int a = start[base], b = start[base + NP];
  for (int k = a + threadIdx.x; k < b; k += blockDim.x) {
    int e = csr[k];
    if (perm[e]) {
      int idx = atomicAdd(&cnt, 1);
      if (idx < 8192) {
        er[idx] = (unsigned short)(ei[e] - base);
        ec[idx] = (unsigned short)(ei[NE + e] - base);
      }
    }
  }
  __syncthreads();
  int m = min(cnt, 8192);
  for (int it = 0; it < CCIT; it++) {
    for (int k = threadIdx.x; k < m; k += blockDim.x) {
      int r = er[k], c = ec[k];
      atomicMin(&lab[r], lab[c]);
      atomicMin(&lab[c], lab[r]);
    }
    __syncthreads();
    for (int i = threadIdx.x; i < NP; i += blockDim.x) tmp[i] = lab[lab[i]];
    __syncthreads();
    for (int i = threadIdx.x; i < NP; i += blockDim.x) lab[i] = tmp[tmp[i]];
    __syncthreads();
  }
  for (int i = threadIdx.x; i < NP; i += blockDim.x) comp[base + i] = base + lab[i];
}

/* ---- GINE aggregate: h = x + segsum(perm ? relu(x[row]+ea2) : 0, col) ---- */
__global__ void k_gine(const float* __restrict__ x, const float* __restrict__ ea2,
                       const int* __restrict__ ei, const unsigned char* __restrict__ perm,
                       const int* __restrict__ start, const int* __restrict__ csr,
                       float* __restrict__ h) {
  int wid = (blockIdx.x*blockDim.x + threadIdx.x) >> 6;
  int lane = threadIdx.x & 63;
  if (wid >= NN) return;
  int a = start[wid], b = start[wid+1];
  float s0 = 0.f, s1 = 0.f;
  for (int k = a; k < b; k++) {
    int e = csr[k];
    if (!perm[e]) continue;
    int r = ei[e];
    const float* pe = ea2 + (size_t)e*D;
    const float* px = x + (size_t)r*D;
    s0 += fmaxf(px[lane]      + pe[lane],      0.f);
    s1 += fmaxf(px[lane + 64] + pe[lane + 64], 0.f);
  }
  h[(size_t)wid*D + lane]      = x[(size_t)wid*D + lane]      + s0;
  h[(size_t)wid*D + lane + 64] = x[(size_t)wid*D + lane + 64] + s1;
}

/* ---- generic row matmul out = act(in@W^T + b) ---- */
__global__ __launch_bounds__(256) void k_rowmm(
    const float* __restrict__ in, const float* __restrict__ wq,
    const float* __restrict__ bias, float* __restrict__ out,
    int nrows, int do_relu) {
  __shared__ float sbuf[4][8*D];
  float* wb = sbuf[threadIdx.x >> 6];
  const int lane = threadIdx.x & 63;
  const int wid = (blockIdx.x*256 + threadIdx.x) >> 6;
  const int nw = (gridDim.x*256) >> 6;
  const float b0r = bias[lane], b1r = bias[lane+64];
  for (int base = wid*8; base < nrows; base += nw*8) {
    float a0[8], a1[8];
#pragma unroll
    for (int t = 0; t < 8; t++) {
      const float* pe = in + (size_t)(base+t)*D;
      wb[t*D + lane]      = pe[lane];
      wb[t*D + lane + 64] = pe[lane+64];
      a0[t] = b0r; a1[t] = b1r;
    }
    mm8l(wq, wb, lane, a0, a1);
#pragma unroll
    for (int t = 0; t < 8; t++) {
      float o0 = a0[t], o1 = a1[t];
      if (do_relu) { o0 = fmaxf(o0, 0.f); o1 = fmaxf(o1, 0.f); }
      float* po = out + (size_t)(base+t)*D;
      po[lane] = o0; po[lane+64] = o1;
    }
  }
}

/* ---- logit + per-component max ---- */
__global__ void k_logit(const float* __restrict__ xs, const float* __restrict__ attnW,
                        const int* __restrict__ comp, float* __restrict__ logit,
                        unsigned* __restrict__ mx) {
  int wid = (blockIdx.x*blockDim.x + threadIdx.x) >> 6;
  int lane = threadIdx.x & 63;
  if (wid >= NN) return;
  float p = xs[(size_t)wid*D + lane]*attnW[lane] + xs[(size_t)wid*D + lane + 64]*attnW[lane + 64];
#pragma unroll
  for (int off = 32; off > 0; off >>= 1) p += __shfl_xor(p, off, 64);
  if (lane == 0) {
    float l = (p >= 0.f) ? p : 0.01f*p;   /* leaky_relu */
    logit[wid] = l;
    atomicMax(&mx[comp[wid]], fenc(l));
  }
}

__global__ void k_expden(const float* __restrict__ logit, const int* __restrict__ comp,
                         const unsigned* __restrict__ mx, float* __restrict__ exv,
                         float* __restrict__ den) {
  int n = blockIdx.x*blockDim.x + threadIdx.x;
  if (n >= NN) return;
  float m = fdec(mx[comp[n]]);
  float e = expf(logit[n] - m);
  exv[n] = e;
  atomicAdd(&den[comp[n]], e);
}

__global__ void k_pool(const float* __restrict__ xs, const float* __restrict__ exv,
                       const float* __restrict__ den, const int* __restrict__ comp,
                       float* __restrict__ xout) {
  int wid = (blockIdx.x*blockDim.x + threadIdx.x) >> 6;
  int lane = threadIdx.x & 63;
  if (wid >= NN) return;
  float w = exv[wid] / den[comp[wid]];
  size_t dst = (size_t)comp[wid]*D;
  atomicAdd(&xout[dst + lane],      w*xs[(size_t)wid*D + lane]);
  atomicAdd(&xout[dst + lane + 64], w*xs[(size_t)wid*D + lane + 64]);
}

/* ---- coalesce: key presence bitmap ---- */
__global__ void k_bitmap(const int* __restrict__ ei, const int* __restrict__ comp,
                         const int* __restrict__ batch, unsigned* __restrict__ bitmap,
                         int* __restrict__ validcnt) {
  __shared__ int lv;
  if (threadIdx.x == 0) lv = 0;
  __syncthreads();
  int stride = blockDim.x*gridDim.x;
  for (int e = blockIdx.x*blockDim.x + threadIdx.x; e < NE; e += stride) {
    int r = ei[e], c = ei[NE + e];
    int rc = comp[r], cc = comp[c];
    if (rc != cc) {
      int g = batch[r];
      int lr = rc - g*NP, lc = cc - g*NP;
      if ((unsigned)lr < NP && (unsigned)lc < NP) {
        int ck = g*KPG + lr*NP + lc;
        atomicOr(&bitmap[ck >> 5], 1u << (ck & 31));
        atomicAdd(&lv, 1);
      }
    }
  }
  __syncthreads();
  if (threadIdx.x == 0) atomicAdd(validcnt, lv);
}

/* ---- popcount prefix scan: per-block ---- */
__global__ __launch_bounds__(256) void k_scan1(const unsigned* __restrict__ bitmap,
                                               unsigned* __restrict__ wpref,
                                               unsigned* __restrict__ bsum) {
  __shared__ unsigned buf[256];
  int i = blockIdx.x*256 + threadIdx.x;
  unsigned v = (i < NWORD) ? (unsigned)__popc(bitmap[i]) : 0u;
  buf[threadIdx.x] = v;
  __syncthreads();
  for (int o = 1; o < 256; o <<= 1) {
    unsigned x = (threadIdx.x >= o) ? buf[threadIdx.x - o] : 0u;
    __syncthreads();
    buf[threadIdx.x] += x;
    __syncthreads();
  }
  if (i < NWORD) wpref[i] = buf[threadIdx.x] - v;
  if (threadIdx.x == 255) bsum[blockIdx.x] = buf[255];
}

__global__ __launch_bounds__(256) void k_scan2(unsigned* __restrict__ bsum,
                                               int* __restrict__ U) {
  __shared__ unsigned buf[256];
  __shared__ unsigned carry;
  int t = threadIdx.x;
  if (t == 0) carry = 0;
  __syncthreads();
  for (int base = 0; base < SCANB; base += 256) {
    int i = base + t;
    unsigned v = (i < SCANB) ? bsum[i] : 0u;
    buf[t] = v; __syncthreads();
    for (int o = 1; o < 256; o <<= 1) {
      unsigned x = (t >= o) ? buf[t-o] : 0u;
      __syncthreads();
      buf[t] += x;
      __syncthreads();
    }
    if (i < SCANB) bsum[i] = carry + buf[t] - v;
    unsigned tot = buf[255];
    __syncthreads();
    if (t == 0) carry += tot;
    __syncthreads();
  }
  if (t == 0) *U = (int)carry;
}

__global__ void k_scan3(unsigned* __restrict__ wpref, const unsigned* __restrict__ bsum) {
  int i = blockIdx.x*256 + threadIdx.x;
  if (i < NWORD) wpref[i] += bsum[blockIdx.x];
}

/* ---- scatter coalesced edge_attr + edge_index ---- */
__global__ void k_coalesce(const int* __restrict__ ei, const int* __restrict__ comp,
                           const int* __restrict__ batch, const float* __restrict__ ea2,
                           const unsigned* __restrict__ bitmap, const unsigned* __restrict__ wpref,
                           float* __restrict__ out) {
  const int lane = threadIdx.x & 63;
  int wid = (blockIdx.x*blockDim.x + threadIdx.x) >> 6;
  int nw = (gridDim.x*blockDim.x) >> 6;
  for (int e = wid; e < NE; e += nw) {
    int r = ei[e], c = ei[NE + e];
    int rc = comp[r], cc = comp[c];
    if (rc == cc) continue;
    int g = batch[r];
    int lr = rc - g*NP, lc = cc - g*NP;
    if ((unsigned)lr >= NP || (unsigned)lc >= NP) continue;
    int ck = g*KPG + lr*NP + lc;
    int wd = ck >> 5, bit = ck & 31;
    unsigned rank = wpref[wd] + (unsigned)__popc(bitmap[wd] & ((1u << bit) - 1u));
    const float* pe = ea2 + (size_t)e*D;
    float* po = out + EAOUT_OFF + (size_t)rank*D;
    atomicAdd(&po[lane],      pe[lane]);
    atomicAdd(&po[lane + 64], pe[lane + 64]);
    if (lane == 0) {
      out[ROW_OFF + rank] = (float)rc;
      out[COL_OFF + rank] = (float)cc;
    }
  }
}

__global__ void k_tail(const int* __restrict__ U, const int* __restrict__ validcnt,
                       float* __restrict__ out) {
  if (blockIdx.x == 0 && threadIdx.x == 0) {
    int u = *U;
    if (*validcnt < NE && u < NE) {
      out[ROW_OFF + u] = -1.0f;
      out[COL_OFF + u] = -1.0f;
    }
  }
}

extern "C" void kernel_launch(void* const* d_in, const int* in_sizes, int n_in,
                              void* d_out, int out_size, void* d_ws, size_t ws_size,
                              hipStream_t stream) {
  const float* x         = (const float*)d_in[0];
  const float* edge_attr = (const float*)d_in[1];
  const float* query     = (const float*)d_in[2];
  const float* qW = (const float*)d_in[3];
  const float* qb = (const float*)d_in[4];
  const float* kW = (const float*)d_in[5];
  const float* kb = (const float*)d_in[6];
  const float* vW = (const float*)d_in[7];
  const float* vb = (const float*)d_in[8];
  const float* prelu_a = (const float*)d_in[9];
  const float* ln_g = (const float*)d_in[10];
  const float* ln_b = (const float*)d_in[11];
  const float* attnW = (const float*)d_in[12];
  const float* g1W = (const float*)d_in[13];
  const float* g1b = (const float*)d_in[14];
  const float* g2W = (const float*)d_in[15];
  const float* g2b = (const float*)d_in[16];
  const int* ei    = (const int*)d_in[17];
  const int* batch = (const int*)d_in[18];
  const int* rev   = (const int*)d_in[19];
  float* out = (float*)d_out;
  (void)in_sizes; (void)n_in; (void)out_size; (void)rev;

  char* w = (char*)d_ws;
  size_t off = 0;
  auto alloc = [&](size_t bytes) -> void* {
    void* p = w + off;
    off = (off + bytes + 255) & ~(size_t)255;
    return p;
  };
  float* ea = (float*)alloc((size_t)NE*D*4);
  float* h  = (float*)alloc((size_t)NN*D*4);   /* msg, then h */
  float* t1 = (float*)alloc((size_t)NN*D*4);
  float* xs = (float*)alloc((size_t)NN*D*4);
  float* Qm = (float*)alloc((size_t)NG*D*4);
  float* qn = (float*)alloc(NG*4);
  float* gmean = (float*)alloc(NG*4);
  float* wTk = (float*)alloc((size_t)D*D*4);
  float* wTv = (float*)alloc((size_t)D*D*4);
  float* wT1 = (float*)alloc((size_t)D*D*4);
  float* wT2 = (float*)alloc((size_t)D*D*4);
  int* comp   = (int*)alloc((size_t)NN*4);
  float* logit = (float*)alloc((size_t)NN*4);
  float* exv   = (float*)alloc((size_t)NN*4);
  int* startc = (int*)alloc((size_t)(NN+1)*4);
  int* csr    = (int*)alloc((size_t)NE*4);
  unsigned char* perm = (unsigned char*)alloc(NE);
  unsigned* wpref = (unsigned*)alloc((size_t)NWORD*4);
  unsigned* bsum  = (unsigned*)alloc((size_t)(SCANB+32)*4);
  int* bsumN = (int*)alloc((size_t)(NBLKN+32)*4);
  int* Uv = (int*)alloc(256);
  unsigned* mx = (unsigned*)alloc((size_t)NN*4);
  /* zero region (single memset) */
  size_t z0 = off;
  int* cnt   = (int*)alloc((size_t)NN*4);
  int* fillc = (int*)alloc((size_t)NN*4);
  float* den = (float*)alloc((size_t)NN*4);
  int* validcnt = (int*)alloc(256);
  unsigned* bitmap = (unsigned*)alloc((size_t)NWORD*4);
  size_t z1 = off;
  if (off > ws_size) return;  /* workspace too small: fail visibly */

  hipMemsetAsync(d_out, 0, OUT_TOTAL*4, stream);
  hipMemsetAsync(w + z0, 0, z1 - z0, stream);

  k_transp<<<256, 256, 0, stream>>>(kW, vW, g1W, g2W, wTk, wTv, wT1, wT2);
  k_init<<<1024, 256, 0, stream>>>(mx, out);
  k_qmat<<<NG, 128, 0, stream>>>(query, qW, qb, Qm, qn);
  k_count<<<512, 256, 0, stream>>>(ei, cnt);
  k_scanA<<<NBLKN, 256, 0, stream>>>(cnt, startc, bsumN);
  k_scanB<<<1, 256, 0, stream>>>(bsumN);
  k_scanC<<<NBLKN, 256, 0, stream>>>(startc, bsumN);
  k_fillcsr<<<512, 256, 0, stream>>>(ei, fillc, startc, csr);
  k_sortcsr<<<(NN+255)/256, 256, 0, stream>>>(startc, csr);
  k_msg<<<NN/4, 256, 0, stream>>>(edge_attr, startc, csr, h);
  k_ea<<<8192, 256, 0, stream>>>(edge_attr, h, x, ei, ea);
  k_score<<<2048, 256, 0, stream>>>(ea, ei, batch, wTk, kb, Qm, qn, out + SCORE_OFF);
  k_mean<<<NG, 256, 0, stream>>>(out + SCORE_OFF, startc, csr, gmean);
  k_vea2<<<2048, 256, 0, stream>>>(ea, out + SCORE_OFF, ei, batch, wTv, vb,
                                   prelu_a, ln_g, ln_b, gmean, perm);
  k_cc<<<NG, 256, 0, stream>>>(ei, perm, startc, csr, comp);
  k_gine<<<NN/4, 256, 0, stream>>>(x, ea, ei, perm, startc, csr, h);
  k_rowmm<<<1024, 256, 0, stream>>>(h, wT1, g1b, t1, NN, 1);
  k_rowmm<<<1024, 256, 0, stream>>>(t1, wT2, g2b, xs, NN, 0);
  k_logit<<<NN/4, 256, 0, stream>>>(xs, attnW, comp, logit, mx);
  k_expden<<<(NN+255)/256, 256, 0, stream>>>(logit, comp, mx, exv, den);
  k_pool<<<NN/4, 256, 0, stream>>>(xs, exv, den, comp, out);
  k_bitmap<<<512, 256, 0, stream>>>(ei, comp, batch, bitmap, validcnt);
  k_scan1<<<SCANB, 256, 0, stream>>>(bitmap, wpref, bsum);
  k_scan2<<<1, 256, 0, stream>>>(bsum, Uv);
  k_scan3<<<SCANB, 256, 0, stream>>>(wpref, bsum);
  k_coalesce<<<2048, 256, 0, stream>>>(ei, comp, batch, ea, bitmap, wpref, out);
  k_tail<<<1, 64, 0, stream>>>(Uv, validcnt, out);
}